// Round 3
// baseline (396.344 us; speedup 1.0000x reference)
//
#include <hip/hip_runtime.h>
#include <cmath>
#include <complex>
#include <algorithm>

// Sparse tensor product (e3nn 'uvu'): 128x0e+128x1o+128x2e (x) 1x0e+1x1o+1x2e -> same as in1.
// One thread per (z,u). CG coeffs computed host-side in fp64 (exact e3nn port), alpha folded,
// passed by value in kernarg. All global I/O float4-coalesced via LDS staging; compute-phase
// LDS reads at strides 1/3/5 (coprime with 32 banks -> only free 2-way aliasing).
// Uses clang ext_vector_type(4) float for the 16B vectors (__builtin_nontemporal_store
// rejects HIP's class-based float4).

namespace {

constexpr int NPATH = 11;
constexpr int P_I1[NPATH] = {0,0,0,1,1,1,1,2,2,2,2};
constexpr int P_I2[NPATH] = {0,1,2,0,1,1,2,0,1,2,2};
constexpr int P_IO[NPATH] = {0,1,2,1,0,2,1,2,1,0,2};
constexpr int DIM_[3]  = {1,3,5};
constexpr int LOFF[3]  = {0,1,4};   // offsets of l-blocks inside a 9-float register set
constexpr int P_OFF[NPATH] = {0,1,10,35,44,53,98,143,168,213,238};
constexpr int CG_TOTAL = 363;
constexpr int ROWF = 1152;          // floats per x1/out row
constexpr int ROWV = ROWF / 4;      // float4 per row (288)

typedef float v4f __attribute__((ext_vector_type(4)));

struct CGPack { float c[CG_TOTAL]; };

// ---------------- host-side e3nn Wigner 3j (real basis) ----------------

double fct(int n){ double r = 1.0; for(int i = 2; i <= n; ++i) r *= i; return r; }

double su2_cg(int j1,int m1,int j2,int m2,int j3,int m3){
  if (m3 != m1 + m2) return 0.0;
  int vmin = std::max(std::max(-j1 + j2 + m3, -j1 + m1), 0);
  int vmax = std::min(std::min(j2 + j3 + m1, j3 - j1 + j2), j3 + m3);
  double C = std::sqrt((2.0*j3 + 1.0) * fct(j3 + j1 - j2) * fct(j3 - j1 + j2) * fct(j1 + j2 - j3)
                       * fct(j3 + m3) * fct(j3 - m3)
                       / (fct(j1 + j2 + j3 + 1) * fct(j1 - m1) * fct(j1 + m1)
                          * fct(j2 - m2) * fct(j2 + m2)));
  double S = 0.0;
  for (int v = vmin; v <= vmax; ++v){
    double t = fct(j2 + j3 + m1 - v) * fct(j1 - m1 + v)
             / (fct(v) * fct(j3 - j1 + j2 - v) * fct(j3 + m3 - v) * fct(v + j1 - j2 - m3));
    S += (((v + j2 + m2) & 1) ? -1.0 : 1.0) * t;
  }
  return C * S;
}

void q_mat(int l, std::complex<double> q[5][5]){
  for (int a = 0; a < 5; ++a) for (int b = 0; b < 5; ++b) q[a][b] = 0.0;
  const double s = 1.0 / std::sqrt(2.0);
  for (int m = -l; m < 0; ++m){
    q[l+m][l-m] = s;
    q[l+m][l+m] = std::complex<double>(0.0, -s);
  }
  q[l][l] = 1.0;
  for (int m = 1; m <= l; ++m){
    double sg = (m & 1) ? -1.0 : 1.0;
    q[l+m][l+m] = sg * s;
    q[l+m][l-m] = std::complex<double>(0.0, sg * s);
  }
  std::complex<double> ph(1.0, 0.0);
  const std::complex<double> mi(0.0, -1.0);
  for (int t = 0; t < l; ++t) ph *= mi;
  for (int a = 0; a < 5; ++a) for (int b = 0; b < 5; ++b) q[a][b] *= ph;
}

void wigner3j(int l1, int l2, int l3, double scale, float* dst){
  const int n1 = 2*l1+1, n2 = 2*l2+1, n3 = 2*l3+1;
  std::complex<double> C[5][5][5];
  for (int a = 0; a < 5; ++a) for (int b = 0; b < 5; ++b) for (int c = 0; c < 5; ++c)
    C[a][b][c] = 0.0;
  for (int m1 = -l1; m1 <= l1; ++m1)
    for (int m2 = -l2; m2 <= l2; ++m2)
      for (int m3 = -l3; m3 <= l3; ++m3)
        C[l1+m1][l2+m2][l3+m3] = su2_cg(l1, m1, l2, m2, l3, m3);
  std::complex<double> Q1[5][5], Q2[5][5], Q3[5][5];
  q_mat(l1, Q1); q_mat(l2, Q2); q_mat(l3, Q3);
  double R[5][5][5];
  double nrm = 0.0;
  for (int a = 0; a < n1; ++a)
    for (int b = 0; b < n2; ++b)
      for (int c = 0; c < n3; ++c){
        std::complex<double> s(0.0, 0.0);
        for (int i = 0; i < n1; ++i)
          for (int k = 0; k < n2; ++k)
            for (int n = 0; n < n3; ++n)
              s += Q1[i][a] * Q2[k][b] * std::conj(Q3[n][c]) * C[i][k][n];
        R[a][b][c] = s.real();
        nrm += s.real() * s.real();
      }
  nrm = std::sqrt(nrm);
  for (int a = 0; a < n1; ++a)
    for (int b = 0; b < n2; ++b)
      for (int c = 0; c < n3; ++c)
        dst[(a*n2 + b)*n3 + c] = (float)(scale * R[a][b][c] / nrm);
}

CGPack build_pack(){
  CGPack p;
  int npaths_to[3] = {0,0,0};
  for (int i = 0; i < NPATH; ++i) npaths_to[P_IO[i]]++;
  for (int i = 0; i < NPATH; ++i){
    double alpha = std::sqrt((double)DIM_[P_IO[i]] / (double)npaths_to[P_IO[i]]);
    wigner3j(P_I1[i], P_I2[i], P_IO[i], alpha, p.c + P_OFF[i]);
  }
  return p;
}

} // namespace

// ---------------- device kernel ----------------

__global__ __launch_bounds__(256) void tp_uvu_kernel(
    const float* __restrict__ x1, const float* __restrict__ x2,
    const float* __restrict__ w, float* __restrict__ out,
    int Z, CGPack cg)
{
  const int tid  = threadIdx.x;
  const int u    = tid & 127;           // mul index 0..127
  const int zloc = tid >> 7;            // 0 or 1 (wave-uniform: each wave has one zloc)
  const long zbase = (long)blockIdx.x * 2;
  const long z     = zbase + zloc;

  __shared__ float s_x1[2 * ROWF];
  __shared__ float s_o [2 * ROWF];
  __shared__ float s_x2[2][9];

  // --- stage 1: cooperative float4 load of both x1 rows into LDS ---
  const int nvalid_v = (int)((Z - zbase >= 2 ? 2 : (Z - zbase)) * ROWV); // valid float4 count
  {
    const v4f* g1 = (const v4f*)(x1 + zbase * ROWF);
    v4f* s1 = (v4f*)s_x1;
    #pragma unroll
    for (int it = 0; it < 3; ++it) {
      int i = tid + it * 256;
      if (i < nvalid_v) s1[i] = g1[i];
    }
  }
  if (z < Z && u < 9) s_x2[zloc][u] = x2[z * 9 + u];
  __syncthreads();

  // --- stage 2: per-(z,u) compute from LDS ---
  const float* x1z = s_x1 + zloc * ROWF;
  float xv2[9];
  #pragma unroll
  for (int j = 0; j < 9; ++j) xv2[j] = s_x2[zloc][j];

  float in1[9];
  in1[0] = x1z[u];
  #pragma unroll
  for (int i = 0; i < 3; ++i) in1[1+i] = x1z[128 + u*3 + i];
  #pragma unroll
  for (int i = 0; i < 5; ++i) in1[4+i] = x1z[512 + u*5 + i];

  float o[9];
  #pragma unroll
  for (int k = 0; k < 9; ++k) o[k] = 0.0f;

  #pragma unroll
  for (int p = 0; p < NPATH; ++p){
    const float wv = w[p * 128 + u];
    const int l1 = P_I1[p], l2 = P_I2[p], lo = P_IO[p];
    const int d1 = DIM_[l1], d2 = DIM_[l2], dd = DIM_[lo];
    const int b1 = LOFF[l1], b2 = LOFF[l2], bo = LOFF[lo];
    #pragma unroll
    for (int i = 0; i < d1; ++i){
      #pragma unroll
      for (int j = 0; j < d2; ++j){
        const float t = wv * in1[b1 + i] * xv2[b2 + j];
        #pragma unroll
        for (int k = 0; k < dd; ++k)
          o[bo + k] = fmaf(t, cg.c[P_OFF[p] + (i*d2 + j)*dd + k], o[bo + k]);
      }
    }
  }

  // --- stage 3: results -> LDS, then cooperative float4 nontemporal stores ---
  {
    float* oz = s_o + zloc * ROWF;
    oz[u] = o[0];
    #pragma unroll
    for (int k = 0; k < 3; ++k) oz[128 + u*3 + k] = o[1+k];
    #pragma unroll
    for (int k = 0; k < 5; ++k) oz[512 + u*5 + k] = o[4+k];
  }
  __syncthreads();
  {
    v4f* g_o = (v4f*)(out + zbase * ROWF);
    const v4f* s1 = (const v4f*)s_o;
    #pragma unroll
    for (int it = 0; it < 3; ++it) {
      int i = tid + it * 256;
      if (i < nvalid_v) __builtin_nontemporal_store(s1[i], &g_o[i]);
    }
  }
}

extern "C" void kernel_launch(void* const* d_in, const int* in_sizes, int n_in,
                              void* d_out, int out_size, void* d_ws, size_t ws_size,
                              hipStream_t stream)
{
  const float* x1 = (const float*)d_in[0];
  const float* x2 = (const float*)d_in[1];
  const float* w  = (const float*)d_in[2];
  float* out = (float*)d_out;
  const int Z = in_sizes[0] / ROWF;

  CGPack pack = build_pack();   // host-only, identical every call

  const int zpb = 2;
  dim3 grid((Z + zpb - 1) / zpb), block(128 * zpb);
  hipLaunchKernelGGL(tp_uvu_kernel, grid, block, 0, stream,
                     x1, x2, w, out, Z, pack);
}

// Round 4
// 383.852 us; speedup vs baseline: 1.0325x; 1.0325x over previous
//
#include <hip/hip_runtime.h>
#include <algorithm>

// Sparse tensor product (e3nn 'uvu'): 128x0e+128x1o+128x2e (x) 1x0e+1x1o+1x2e -> same as in1.
// One thread per (z,u). CG coefficients are computed at COMPILE TIME (constexpr port of
// e3nn su2_cg / real<->complex basis change / Frobenius norm, alpha folded in), so all
// structurally-zero Wigner-3j entries fold away and the contraction becomes straight-line
// FMAs on literals (~130 FMA vs 363 dense). Global I/O float4-coalesced via LDS staging.

namespace {

constexpr int NPATH = 11;
constexpr int P_I1[NPATH] = {0,0,0,1,1,1,1,2,2,2,2};
constexpr int P_I2[NPATH] = {0,1,2,0,1,1,2,0,1,2,2};
constexpr int P_IO[NPATH] = {0,1,2,1,0,2,1,2,1,0,2};
constexpr int DIM_[3]  = {1,3,5};
constexpr int LOFF[3]  = {0,1,4};
constexpr int P_OFF[NPATH] = {0,1,10,35,44,53,98,143,168,213,238};
constexpr int CG_TOTAL = 363;
constexpr int ROWF = 1152;          // floats per x1/out row
constexpr int ROWV = ROWF / 4;      // float4 per row (288)

typedef float v4f __attribute__((ext_vector_type(4)));

struct CGPack { float c[CG_TOTAL]; };

// ---------------- compile-time e3nn Wigner 3j (real basis) ----------------

constexpr double cfct(int n){ double r = 1.0; for (int i = 2; i <= n; ++i) r *= i; return r; }

constexpr double csqrt(double x){
  if (x <= 0.0) return 0.0;
  double g = x > 1.0 ? x : 1.0;
  for (int i = 0; i < 64; ++i) g = 0.5 * (g + x / g);
  return g;
}

struct cplx { double re = 0.0, im = 0.0; };
constexpr cplx cmul(cplx a, cplx b){ return {a.re*b.re - a.im*b.im, a.re*b.im + a.im*b.re}; }
constexpr cplx cconj(cplx a){ return {a.re, -a.im}; }

constexpr double su2_cg(int j1,int m1,int j2,int m2,int j3,int m3){
  if (m3 != m1 + m2) return 0.0;
  int vmin = std::max(std::max(-j1 + j2 + m3, -j1 + m1), 0);
  int vmax = std::min(std::min(j2 + j3 + m1, j3 - j1 + j2), j3 + m3);
  double C = csqrt((2.0*j3 + 1.0) * cfct(j3 + j1 - j2) * cfct(j3 - j1 + j2) * cfct(j1 + j2 - j3)
                   * cfct(j3 + m3) * cfct(j3 - m3)
                   / (cfct(j1 + j2 + j3 + 1) * cfct(j1 - m1) * cfct(j1 + m1)
                      * cfct(j2 - m2) * cfct(j2 + m2)));
  double S = 0.0;
  for (int v = vmin; v <= vmax; ++v){
    double t = cfct(j2 + j3 + m1 - v) * cfct(j1 - m1 + v)
             / (cfct(v) * cfct(j3 - j1 + j2 - v) * cfct(j3 + m3 - v) * cfct(v + j1 - j2 - m3));
    S += (((v + j2 + m2) & 1) ? -1.0 : 1.0) * t;
  }
  return C * S;
}

struct QM { cplx q[5][5]; };

constexpr QM q_mat(int l){
  QM Q{};
  const double s = 1.0 / csqrt(2.0);
  for (int m = -l; m < 0; ++m){
    Q.q[l+m][l-m] = {s, 0.0};
    Q.q[l+m][l+m] = {0.0, -s};
  }
  Q.q[l][l] = {1.0, 0.0};
  for (int m = 1; m <= l; ++m){
    double sg = (m & 1) ? -1.0 : 1.0;
    Q.q[l+m][l+m] = {sg * s, 0.0};
    Q.q[l+m][l-m] = {0.0, sg * s};
  }
  cplx ph{1.0, 0.0};
  for (int t = 0; t < l; ++t) ph = cmul(ph, {0.0, -1.0});   // (-i)^l
  for (int a = 0; a < 5; ++a) for (int b = 0; b < 5; ++b) Q.q[a][b] = cmul(Q.q[a][b], ph);
  return Q;
}

constexpr void wigner3j(int l1, int l2, int l3, double scale, float* dst){
  const int n1 = 2*l1+1, n2 = 2*l2+1, n3 = 2*l3+1;
  const QM Q1 = q_mat(l1), Q2 = q_mat(l2), Q3 = q_mat(l3);
  double R[5][5][5] = {};
  double nrm = 0.0;
  for (int a = 0; a < n1; ++a){
    const int il[2] = {a, n1 - 1 - a}; const int ic = (il[0] == il[1]) ? 1 : 2;
    for (int b = 0; b < n2; ++b){
      const int kl[2] = {b, n2 - 1 - b}; const int kc = (kl[0] == kl[1]) ? 1 : 2;
      for (int c = 0; c < n3; ++c){
        const int nl[2] = {c, n3 - 1 - c}; const int nc = (nl[0] == nl[1]) ? 1 : 2;
        cplx s{0.0, 0.0};
        for (int ii = 0; ii < ic; ++ii)
          for (int kk = 0; kk < kc; ++kk)
            for (int nn = 0; nn < nc; ++nn){
              const int i = il[ii], k = kl[kk], n = nl[nn];
              // C[i][k][n] in the complex basis (su2_cg with m-offsets)
              const double cg = su2_cg(l1, i - l1, l2, k - l2, l3, n - l3);
              if (cg == 0.0) continue;
              cplx t = cmul(Q1.q[i][a], Q2.q[k][b]);
              t = cmul(t, cconj(Q3.q[n][c]));
              s.re += t.re * cg; s.im += t.im * cg;
            }
        R[a][b][c] = s.re;
        nrm += s.re * s.re;
      }
    }
  }
  nrm = csqrt(nrm);
  for (int a = 0; a < n1; ++a)
    for (int b = 0; b < n2; ++b)
      for (int c = 0; c < n3; ++c){
        double v = scale * R[a][b][c] / nrm;
        // flush tiny numerical dust to exact zero so the kernel folds it away
        if (v < 1e-10 && v > -1e-10) v = 0.0;
        dst[(a*n2 + b)*n3 + c] = (float)v;
      }
}

constexpr CGPack build_pack(){
  CGPack p{};
  int npaths_to[3] = {0,0,0};
  for (int i = 0; i < NPATH; ++i) npaths_to[P_IO[i]]++;
  for (int i = 0; i < NPATH; ++i){
    double alpha = csqrt((double)DIM_[P_IO[i]] / (double)npaths_to[P_IO[i]]);
    wigner3j(P_I1[i], P_I2[i], P_IO[i], alpha, p.c + P_OFF[i]);
  }
  return p;
}

constexpr CGPack CG = build_pack();

} // namespace

// ---------------- device kernel ----------------

__global__ __launch_bounds__(256) void tp_uvu_kernel(
    const float* __restrict__ x1, const float* __restrict__ x2,
    const float* __restrict__ w, float* __restrict__ out,
    int Z)
{
  const int tid  = threadIdx.x;
  const int u    = tid & 127;           // mul index 0..127
  const int zloc = tid >> 7;            // 0 or 1 (wave-uniform)
  const long zbase = (long)blockIdx.x * 2;
  const long z     = zbase + zloc;

  __shared__ float s_x1[2 * ROWF];
  __shared__ float s_o [2 * ROWF];
  __shared__ float s_x2[2][9];

  // --- stage 1: cooperative float4 load of both x1 rows into LDS ---
  const int nvalid_v = (int)((Z - zbase >= 2 ? 2 : (Z - zbase)) * ROWV);
  {
    const v4f* g1 = (const v4f*)(x1 + zbase * ROWF);
    v4f* s1 = (v4f*)s_x1;
    #pragma unroll
    for (int it = 0; it < 3; ++it) {
      int i = tid + it * 256;
      if (i < nvalid_v) s1[i] = g1[i];
    }
  }
  if (z < Z && u < 9) s_x2[zloc][u] = x2[z * 9 + u];
  __syncthreads();

  // --- stage 2: per-(z,u) compute from LDS ---
  const float* x1z = s_x1 + zloc * ROWF;
  float xv2[9];
  #pragma unroll
  for (int j = 0; j < 9; ++j) xv2[j] = s_x2[zloc][j];

  float wvv[NPATH];
  #pragma unroll
  for (int p = 0; p < NPATH; ++p) wvv[p] = w[p * 128 + u];

  float in1[9];
  in1[0] = x1z[u];
  #pragma unroll
  for (int i = 0; i < 3; ++i) in1[1+i] = x1z[128 + u*3 + i];
  #pragma unroll
  for (int i = 0; i < 5; ++i) in1[4+i] = x1z[512 + u*5 + i];

  float o[9];
  #pragma unroll
  for (int k = 0; k < 9; ++k) o[k] = 0.0f;

  #pragma unroll
  for (int p = 0; p < NPATH; ++p){
    const float wv = wvv[p];
    const int l1 = P_I1[p], l2 = P_I2[p], lo = P_IO[p];
    const int d1 = DIM_[l1], d2 = DIM_[l2], dd = DIM_[lo];
    const int b1 = LOFF[l1], b2 = LOFF[l2], bo = LOFF[lo];
    #pragma unroll
    for (int i = 0; i < d1; ++i){
      #pragma unroll
      for (int j = 0; j < d2; ++j){
        const float t = wv * in1[b1 + i] * xv2[b2 + j];   // DCE'd if all cgv below are 0
        #pragma unroll
        for (int k = 0; k < dd; ++k){
          const float cgv = CG.c[P_OFF[p] + (i*d2 + j)*dd + k];  // compile-time literal
          if (cgv != 0.0f)
            o[bo + k] = fmaf(t, cgv, o[bo + k]);
        }
      }
    }
  }

  // --- stage 3: results -> LDS, then cooperative float4 nontemporal stores ---
  {
    float* oz = s_o + zloc * ROWF;
    oz[u] = o[0];
    #pragma unroll
    for (int k = 0; k < 3; ++k) oz[128 + u*3 + k] = o[1+k];
    #pragma unroll
    for (int k = 0; k < 5; ++k) oz[512 + u*5 + k] = o[4+k];
  }
  __syncthreads();
  {
    v4f* g_o = (v4f*)(out + zbase * ROWF);
    const v4f* s1 = (const v4f*)s_o;
    #pragma unroll
    for (int it = 0; it < 3; ++it) {
      int i = tid + it * 256;
      if (i < nvalid_v) __builtin_nontemporal_store(s1[i], &g_o[i]);
    }
  }
}

extern "C" void kernel_launch(void* const* d_in, const int* in_sizes, int n_in,
                              void* d_out, int out_size, void* d_ws, size_t ws_size,
                              hipStream_t stream)
{
  const float* x1 = (const float*)d_in[0];
  const float* x2 = (const float*)d_in[1];
  const float* w  = (const float*)d_in[2];
  float* out = (float*)d_out;
  const int Z = in_sizes[0] / ROWF;

  const int zpb = 2;
  dim3 grid((Z + zpb - 1) / zpb), block(128 * zpb);
  hipLaunchKernelGGL(tp_uvu_kernel, grid, block, 0, stream,
                     x1, x2, w, out, Z);
}